// Round 11
// baseline (176.535 us; speedup 1.0000x reference)
//
#include <hip/hip_runtime.h>
#include <hip/hip_bf16.h>
#include <stdint.h>

// Shape fixed by reference: B=2, S=1024 -> M=2048; N=4096; K=4096
#define M_DIM 2048
#define N_DIM 4096
#define K_DIM 4096

#define BM 128
#define BN 128
#define BK 64             // int8 elements per K-tile = 64 B per row

#define NSLOT 3           // ring -> 2-deep prefetch -> counted vmcnt(2)
#define ASLOT (BM * BK)   // 8 KiB per A slot
#define BSLOT (BN * BK)   // 8 KiB per B slot
#define NT (K_DIM / BK)   // 64 K-tiles

typedef __attribute__((ext_vector_type(4))) int   int4v;
typedef __attribute__((ext_vector_type(4))) float f32x4;

__device__ __forceinline__ void load_lds16(const void* g, void* l) {
    __builtin_amdgcn_global_load_lds(
        (const __attribute__((address_space(1))) void*)g,
        (__attribute__((address_space(3))) void*)l,
        16, 0, 0);
}

// ---------- x: fp32 [M,K] -> int8 per-row dynamic quant; sx[row] = rowmax/127 ----------
__global__ __launch_bounds__(256) void quant_x(const float* __restrict__ x,
                                               int8_t* __restrict__ Aq,
                                               float* __restrict__ sx) {
    const int row = blockIdx.x;
    const int tid = threadIdx.x;
    const float4* xr = (const float4*)(x + (size_t)row * K_DIM);

    float4 v[4];
    float mx = 0.f;
#pragma unroll
    for (int p = 0; p < 4; p++) {
        v[p] = xr[p * 256 + tid];
        mx = fmaxf(mx, fmaxf(fmaxf(fabsf(v[p].x), fabsf(v[p].y)),
                             fmaxf(fabsf(v[p].z), fabsf(v[p].w))));
    }
#pragma unroll
    for (int off = 32; off >= 1; off >>= 1)
        mx = fmaxf(mx, __shfl_xor(mx, off, 64));

    __shared__ float wmax[4];
    __shared__ float smax;
    if ((tid & 63) == 0) wmax[tid >> 6] = mx;
    __syncthreads();
    if (tid == 0) {
        float m = fmaxf(fmaxf(wmax[0], wmax[1]), fmaxf(wmax[2], wmax[3]));
        m = fmaxf(m, 1e-20f);
        smax = m;
        sx[row] = m * (1.0f / 127.0f);
    }
    __syncthreads();
    const float inv = 127.0f / smax;

    int* out = (int*)Aq + (size_t)row * (K_DIM / 4);
#pragma unroll
    for (int p = 0; p < 4; p++) {
        int q0 = (int)__builtin_rintf(v[p].x * inv);
        int q1 = (int)__builtin_rintf(v[p].y * inv);
        int q2 = (int)__builtin_rintf(v[p].z * inv);
        int q3 = (int)__builtin_rintf(v[p].w * inv);
        q0 = max(-127, min(127, q0)); q1 = max(-127, min(127, q1));
        q2 = max(-127, min(127, q2)); q3 = max(-127, min(127, q3));
        out[p * 256 + tid] = (q0 & 255) | ((q1 & 255) << 8) |
                             ((q2 & 255) << 16) | ((q3 & 255) << 24);
    }
}

// ---------- w: int32 [N,K] (values in [-128,127]) -> int8, exact narrowing ----------
__global__ __launch_bounds__(256) void cvt_w8(const int* __restrict__ w,
                                              int8_t* __restrict__ Bq) {
    size_t i = ((size_t)blockIdx.x * 256 + threadIdx.x) * 16;
    int4 a0 = *(const int4*)(w + i);
    int4 a1 = *(const int4*)(w + i + 4);
    int4 a2 = *(const int4*)(w + i + 8);
    int4 a3 = *(const int4*)(w + i + 12);
    uint4 t;
    t.x = (a0.x & 255) | ((a0.y & 255) << 8) | ((a0.z & 255) << 16) | ((a0.w & 255) << 24);
    t.y = (a1.x & 255) | ((a1.y & 255) << 8) | ((a1.z & 255) << 16) | ((a1.w & 255) << 24);
    t.z = (a2.x & 255) | ((a2.y & 255) << 8) | ((a2.z & 255) << 16) | ((a2.w & 255) << 24);
    t.w = (a3.x & 255) | ((a3.y & 255) << 8) | ((a3.z & 255) << 16) | ((a3.w & 255) << 24);
    *(uint4*)(Bq + i) = t;
}

// ---------- GEMM: C = Aq[M,K] x Bq[N,K]^T (i8 MFMA, i32 acc), epilogue dequant ----------
// r15: counted-vmcnt ring AT 2 BLOCKS/CU -- the one untested combination.
// r4 (best, 40.7us): 2-blk coverage but vmcnt(0) drain per tile. r6/r11: counted
// vmcnt but 1 blk/CU (no coverage). r13: shape change -> bank conflicts. Here:
// BK=64 shrinks slots to 8KB so a 3-slot ring fits 48KB/block -> 2 blocks/CU,
// 16 waves/CU, and the glds queue is NEVER drained mid-loop (steady vmcnt(2):
// tile t's 2 loads proven done, t+1/t+2's stay in flight across the barrier).
// Per tile: {vmcnt(2); s_barrier; 2 glds (stage t+2); 6 ds_read; 8 MFMA}.
// Bank-conflict-free BK=64 layout (row-pair lines): LDS 16B slot S of line L
// (addr = L*128 + S*16) holds global (row = 2L + (e>>2), colgroup = e&3) where
// e = S ^ (L&7). Staging: thread t -> (L = t>>3, S = t&7), LDS addr 16t (linear,
// glds rule). Read af[i]/bf[j]: row = w? + i*16 + l16 -> line = (w?+i*16)/2 +
// (l16>>1) [w?/2 and i*8 are mult of 8 -> line&7 = l16>>1], slot =
// ((l16&1)<<2 | quad) ^ (l16>>1). Per quarter-wave: 8 slots x 2 lanes x 2 rows
// -- identical conflict structure to r4's measured-zero pattern.
// Fragment semantics = r4 at BK=64: af = A[row][k0 + quad*16..+15] identity
// k-chunks, same per-lane map for A and B -> lane->k permutation cancels.
// Slot-reuse safety: a wave reaches barrier(t) only after its tile-(t-1) ds_reads
// completed (compiler lgkm waits precede the consuming MFMAs), and slot (t+2)%3
// == (t-1)%3 is staged only after barrier(t) -> race-free (r6-verified argument).

__global__ __launch_bounds__(512, 4) void gemm_bt_i8(
    const int8_t* __restrict__ A,      // [M,K] int8
    const int8_t* __restrict__ B,      // [N,K] int8
    const float*  __restrict__ sx,     // [M] row dequant scale
    const float*  __restrict__ scales, // [N]
    const float*  __restrict__ bias,   // [N]
    float* __restrict__ C)             // [M,N]
{
    __shared__ __align__(16) int8_t As[NSLOT * ASLOT];  // 24 KiB
    __shared__ __align__(16) int8_t Bs[NSLOT * BSLOT];  // 24 KiB

    const int tid  = threadIdx.x;
    const int bm   = blockIdx.y;
    const int bn   = blockIdx.x;
    const int lane = tid & 63;
    const int wave = tid >> 6;           // 0..7
    const int wm   = (wave >> 2) * 64;   // 0 or 64
    const int wn   = (wave & 3) * 32;    // 0,32,64,96
    const int l16  = lane & 15;
    const int quad = lane >> 4;

    // Staging source (bijection per 128B line): thread t -> line t>>3, slot t&7;
    // e = slot ^ (line&7); global row = 2*line + (e>>2), col byte = (e&3)*16.
    const int e    = (tid & 7) ^ ((tid >> 3) & 7);
    const int arow = 2 * (tid >> 3) + (e >> 2);     // 0..127
    const int acol = (e & 3) * 16;

    const int8_t* ga = A + (size_t)(bm * BM + arow) * K_DIM + acol;
    const int8_t* gb = B + (size_t)(bn * BN + arow) * K_DIM + acol;
    const int la = tid * 16;

#define STAGE(slot, k0_) do {                                    \
        load_lds16(ga + (k0_), As + (slot) * ASLOT + la);        \
        load_lds16(gb + (k0_), Bs + (slot) * BSLOT + la);        \
    } while (0)

    // Read offsets (thread-constant): addr = base + {i,j}*1024 within a slot.
    const int lslot = (((l16 & 1) << 2) | quad) ^ (l16 >> 1);
    const int lpart = (l16 >> 1) * 128 + lslot * 16;
    const int abase = wm * 64 + lpart;   // row-line base: (wm/2)*128 == wm*64
    const int bbase = wn * 64 + lpart;

    int4v acc[4][2] = {};

#define COMPUTE(s_) do {                                                     \
        const int8_t* Ab = As + (s_) * ASLOT;                                \
        const int8_t* Bb = Bs + (s_) * BSLOT;                                \
        int4v af[4], bf[2];                                                  \
        _Pragma("unroll")                                                    \
        for (int i = 0; i < 4; i++)                                          \
            af[i] = *(const int4v*)(Ab + abase + i * 1024);                  \
        _Pragma("unroll")                                                    \
        for (int j = 0; j < 2; j++)                                          \
            bf[j] = *(const int4v*)(Bb + bbase + j * 1024);                  \
        _Pragma("unroll")                                                    \
        for (int i = 0; i < 4; i++)                                          \
            _Pragma("unroll")                                                \
            for (int j = 0; j < 2; j++)                                      \
                acc[i][j] = __builtin_amdgcn_mfma_i32_16x16x64_i8(           \
                    af[i], bf[j], acc[i][j], 0, 0, 0);                       \
    } while (0)

    // Prologue: tiles 0,1 staged (4 loads in flight).
    STAGE(0, 0);
    STAGE(1, BK);

    int s0 = 0, s1 = 1, s2 = 2;
    for (int t = 0; t < NT - 1; ++t) {
        // Oldest 2 (tile t's) complete; tile t+1's (and t+2's after STAGE) fly on.
        asm volatile("s_waitcnt vmcnt(2)" ::: "memory");
        __builtin_amdgcn_s_barrier();
        if (t + 2 < NT)
            STAGE(s2, (t + 2) * BK);
        COMPUTE(s0);
        const int tmp = s0; s0 = s1; s1 = s2; s2 = tmp;
    }
    // Last tile: drain remaining 2.
    asm volatile("s_waitcnt vmcnt(0)" ::: "memory");
    __builtin_amdgcn_s_barrier();
    COMPUTE(s0);

#undef STAGE
#undef COMPUTE

    // Row dequant scales for this lane's 16 output rows.
    float sxr[16];
#pragma unroll
    for (int i = 0; i < 4; i++)
#pragma unroll
        for (int r = 0; r < 4; r++)
            sxr[i * 4 + r] = sx[bm * BM + wm + i * 16 + quad * 4 + r];

    // Epilogue. C/D layout (shape-determined, verified): col = lane&15, row = quad*4 + reg.
#pragma unroll
    for (int j = 0; j < 2; j++) {
        const int col = bn * BN + wn + j * 16 + l16;
        const float s = scales[col];
        const float b = bias[col];
#pragma unroll
        for (int i = 0; i < 4; i++) {
            const int row0 = bm * BM + wm + i * 16 + quad * 4;
#pragma unroll
            for (int r = 0; r < 4; r++) {
                C[(size_t)(row0 + r) * N_DIM + col] =
                    (float)acc[i][j][r] * (sxr[i * 4 + r] * s) + b;
            }
        }
    }
}

// ---------- launch ----------

extern "C" void kernel_launch(void* const* d_in, const int* in_sizes, int n_in,
                              void* d_out, int out_size, void* d_ws, size_t ws_size,
                              hipStream_t stream) {
    const float* x      = (const float*)d_in[0];   // [2,1024,4096] fp32
    const int*   w      = (const int*)d_in[1];     // [4096,4096] int, values in [-128,127]
    const float* scales = (const float*)d_in[2];   // [4096]
    const float* bias   = (const float*)d_in[3];   // [4096]
    float*       out    = (float*)d_out;           // [2,1024,4096] fp32

    int8_t* Aq = (int8_t*)d_ws;                                        // 8 MiB
    int8_t* Bq = (int8_t*)d_ws + (size_t)M_DIM * K_DIM;                // 16 MiB
    float*  sx = (float*)((int8_t*)d_ws + (size_t)(M_DIM + N_DIM) * K_DIM); // 8 KiB

    quant_x<<<M_DIM, 256, 0, stream>>>(x, Aq, sx);
    cvt_w8<<<(int)((size_t)N_DIM * K_DIM / 16 / 256), 256, 0, stream>>>(w, Bq);

    dim3 grid(N_DIM / BN, M_DIM / BM);  // (32, 16) = 512 blocks
    gemm_bt_i8<<<grid, 512, 0, stream>>>(Aq, Bq, sx, scales, bias, out);
}